// Round 3
// baseline (732.234 us; speedup 1.0000x reference)
//
#include <hip/hip_runtime.h>
#include <hip/hip_bf16.h>

// ReprogrammingLayer: q=QWq+bq; k=KsWk+bk; v=VsWv+bv (8 heads, E=128);
// A=softmax(qk^T/sqrt(512)); out=(Av)Wo+bo.
// I/O is FP32 (per reference dtypes); internal compute bf16 MFMA + fp32 accum
// (harness threshold = 2% of absmax, the bf16-tolerant mode).
//
// ws layout (bf16 elems, peak 33M = 66MB):
//   qb[8M]@0 | kb[2M]@8M | vtb[2M]@10M | at[8M]@12M
//   WqT[1M]@20M | WkT[4M]@21M | WvT[4M]@25M | WoT[4M]@29M

typedef __bf16 bf16x8 __attribute__((ext_vector_type(8)));
typedef float  f32x4  __attribute__((ext_vector_type(4)));

union V16 { uint4 u; bf16x8 v; };
__device__ __forceinline__ bf16x8 ld16v(const void* p) {
  V16 t; t.u = *(const uint4*)p; return t.v;
}
__device__ __forceinline__ uint4 pack8(float4 a, float4 b) {
  V16 t;
  t.v[0] = (__bf16)a.x; t.v[1] = (__bf16)a.y; t.v[2] = (__bf16)a.z; t.v[3] = (__bf16)a.w;
  t.v[4] = (__bf16)b.x; t.v[5] = (__bf16)b.y; t.v[6] = (__bf16)b.z; t.v[7] = (__bf16)b.w;
  return t.u;
}

// -------- weight transpose+convert: W[K][N] fp32 -> Wt[N][K] bf16 --------
__global__ __launch_bounds__(256) void transpose_k(const float* __restrict__ W,
                                                   __bf16* __restrict__ Wt, int K, int N) {
  __shared__ __bf16 t[32][33];
  int tx = threadIdx.x & 31, ty = threadIdx.x >> 5;
  int n0 = blockIdx.x * 32, k0 = blockIdx.y * 32;
#pragma unroll
  for (int r = 0; r < 32; r += 8) t[ty + r][tx] = (__bf16)W[(size_t)(k0 + ty + r) * N + n0 + tx];
  __syncthreads();
#pragma unroll
  for (int r = 0; r < 32; r += 8) Wt[(size_t)(n0 + ty + r) * K + k0 + tx] = t[tx][ty + r];
}

// -------- GEMM core: C = A[M,K] @ Bt[N,K]^T + bias --------
// 128x128 tile, BK=32, 4 waves 2x2, 4x4 16x16x32 bf16 mfma frags.
// AT = float (stage converts fp32->bf16) or __bf16 (direct 16B copy).
// CT = __bf16 (intermediates) or float (final output). trans=1 (bf16 only):
// store C^T[N][M] packed 4x.
template <typename AT, typename CT>
__device__ __forceinline__ void gemm_core(__bf16 (*As)[40], __bf16 (*Bs)[40],
                                          const AT* __restrict__ A,
                                          const __bf16* __restrict__ Bt,
                                          const float* __restrict__ bias,
                                          CT* __restrict__ C,
                                          int M, int N, int K, int lda, int trans,
                                          int m0, int n0) {
  const int tid = threadIdx.x;
  const int lane = tid & 63, wave = tid >> 6;
  const int g = lane >> 4, l16 = lane & 15;
  const int wr = wave >> 1, wc = wave & 1;
  f32x4 acc[4][4] = {};
  for (int k0 = 0; k0 < K; k0 += 32) {
    __syncthreads();
#pragma unroll
    for (int i = 0; i < 2; i++) {          // stage 128x32 A-tile + 128x32 Bt-tile
      int c = tid + i * 256;
      int row = c >> 2, col = (c & 3) * 8;
      if constexpr (sizeof(AT) == 4) {     // fp32 -> bf16 convert on stage
        const float* ap = (const float*)A + (size_t)(m0 + row) * lda + k0 + col;
        float4 f0 = *(const float4*)ap;
        float4 f1 = *(const float4*)(ap + 4);
        *(uint4*)&As[row][col] = pack8(f0, f1);
      } else {
        *(uint4*)&As[row][col] = *(const uint4*)((const __bf16*)A + (size_t)(m0 + row) * lda + k0 + col);
      }
      *(uint4*)&Bs[row][col] = *(const uint4*)(Bt + (size_t)(n0 + row) * (size_t)K + k0 + col);
    }
    __syncthreads();
    bf16x8 af[4], bff[4];
#pragma unroll
    for (int mf = 0; mf < 4; mf++) af[mf]  = ld16v(&As[wr * 64 + mf * 16 + l16][g * 8]);
#pragma unroll
    for (int nf = 0; nf < 4; nf++) bff[nf] = ld16v(&Bs[wc * 64 + nf * 16 + l16][g * 8]);
#pragma unroll
    for (int mf = 0; mf < 4; mf++)
#pragma unroll
      for (int nf = 0; nf < 4; nf++)
        acc[mf][nf] = __builtin_amdgcn_mfma_f32_16x16x32_bf16(af[mf], bff[nf], acc[mf][nf], 0, 0, 0);
  }
#pragma unroll
  for (int nf = 0; nf < 4; nf++) {
    int col = n0 + wc * 64 + nf * 16 + l16;
    float bv = bias[col];
#pragma unroll
    for (int mf = 0; mf < 4; mf++) {
      int rowb = m0 + wr * 64 + mf * 16 + g * 4;
      if constexpr (sizeof(CT) == 2) {
        if (trans) {
          union { __bf16 h[4]; uint2 u; } pk;
#pragma unroll
          for (int r = 0; r < 4; r++) pk.h[r] = (__bf16)(acc[mf][nf][r] + bv);
          *(uint2*)&((__bf16*)C)[(size_t)col * M + rowb] = pk.u;   // C^T[n][m]
        } else {
#pragma unroll
          for (int r = 0; r < 4; r++)
            ((__bf16*)C)[(size_t)(rowb + r) * N + col] = (__bf16)(acc[mf][nf][r] + bv);
        }
      } else {
#pragma unroll
        for (int r = 0; r < 4; r++)
          ((float*)C)[(size_t)(rowb + r) * N + col] = acc[mf][nf][r] + bv;
      }
    }
  }
}

// fp32 A -> bf16 C (q projection)
__global__ __launch_bounds__(256) void gemm_f_b(const float* __restrict__ A,
                                                const __bf16* __restrict__ Bt,
                                                const float* __restrict__ bias,
                                                __bf16* __restrict__ C,
                                                int M, int N, int K, int lda, int trans) {
  __shared__ __bf16 As[128][40];
  __shared__ __bf16 Bs[128][40];
  gemm_core<float, __bf16>(As, Bs, A, Bt, bias, C, M, N, K, lda, trans,
                           blockIdx.x * 128, blockIdx.y * 128);
}

// bf16 A -> fp32 C (output projection)
__global__ __launch_bounds__(256) void gemm_b_f(const __bf16* __restrict__ A,
                                                const __bf16* __restrict__ Bt,
                                                const float* __restrict__ bias,
                                                float* __restrict__ C,
                                                int M, int N, int K, int lda, int trans) {
  __shared__ __bf16 As[128][40];
  __shared__ __bf16 Bs[128][40];
  gemm_core<__bf16, float>(As, Bs, A, Bt, bias, C, M, N, K, lda, trans,
                           blockIdx.x * 128, blockIdx.y * 128);
}

// k and v projections merged (fp32 A, bf16 C; v written transposed)
__global__ __launch_bounds__(256) void gemm_kv(const float* __restrict__ A0, const __bf16* __restrict__ B0t,
                                               const float* __restrict__ b0, __bf16* __restrict__ C0,
                                               const float* __restrict__ A1, const __bf16* __restrict__ B1t,
                                               const float* __restrict__ b1, __bf16* __restrict__ C1) {
  __shared__ __bf16 As[128][40];
  __shared__ __bf16 Bs[128][40];
  if (blockIdx.z == 0)
    gemm_core<float, __bf16>(As, Bs, A0, B0t, b0, C0, 2048, 1024, 4096, 4096, 0,
                             blockIdx.x * 128, blockIdx.y * 128);
  else
    gemm_core<float, __bf16>(As, Bs, A1, B1t, b1, C1, 2048, 1024, 4096, 4096, 1,
                             blockIdx.x * 128, blockIdx.y * 128);
}

// -------- flash attention (all operands bf16 in ws) --------
// grid (64 q-blocks, 8 heads), 256 thr. Block: 128 q-rows; S-tile 64.
__global__ __launch_bounds__(256) void attn_k(const __bf16* __restrict__ q,
                                              const __bf16* __restrict__ k,
                                              const __bf16* __restrict__ vt,
                                              __bf16* __restrict__ o) {
  __shared__ __bf16 ks[64][136];   // +8 pad: 272B rows, 16B-aligned
  __shared__ __bf16 vs[128][72];   // [e][s]
  __shared__ __bf16 ps[128][72];   // [q][s]
  const int tid = threadIdx.x, lane = tid & 63, wave = tid >> 6;
  const int g = lane >> 4, l16 = lane & 15;
  const int h = blockIdx.y, q0 = blockIdx.x * 128;
  const float scale = 0.044194173824159216f;  // 1/sqrt(512): d_llm//H per reference

  bf16x8 qf[2][4];
#pragma unroll
  for (int mf = 0; mf < 2; mf++)
#pragma unroll
    for (int kk = 0; kk < 4; kk++) {
      int row = q0 + wave * 32 + mf * 16 + l16;
      qf[mf][kk] = ld16v(q + (size_t)row * 1024 + h * 128 + kk * 32 + g * 8);
    }

  f32x4 accO[2][8] = {};
  float m_i[2][4], l_i[2][4];
#pragma unroll
  for (int a = 0; a < 2; a++)
#pragma unroll
    for (int b = 0; b < 4; b++) { m_i[a][b] = -1e30f; l_i[a][b] = 0.f; }

  for (int s0 = 0; s0 < 2048; s0 += 64) {
    __syncthreads();
#pragma unroll
    for (int i = 0; i < 4; i++) {           // stage K [64s][128e], V^T [128e][64s]
      int c = tid + i * 256;
      { int row = c >> 4, col = (c & 15) * 8;
        *(uint4*)&ks[row][col] = *(const uint4*)(k + (size_t)(s0 + row) * 1024 + h * 128 + col); }
      { int row = c >> 3, col = (c & 7) * 8;
        *(uint4*)&vs[row][col] = *(const uint4*)(vt + (size_t)(h * 128 + row) * 2048 + s0 + col); }
    }
    __syncthreads();

    f32x4 sc[2][4] = {};
#pragma unroll
    for (int kk = 0; kk < 4; kk++) {        // contract over e=128
      bf16x8 kf[4];
#pragma unroll
      for (int nf = 0; nf < 4; nf++) kf[nf] = ld16v(&ks[nf * 16 + l16][kk * 32 + g * 8]);
#pragma unroll
      for (int mf = 0; mf < 2; mf++)
#pragma unroll
        for (int nf = 0; nf < 4; nf++)
          sc[mf][nf] = __builtin_amdgcn_mfma_f32_16x16x32_bf16(qf[mf][kk], kf[nf], sc[mf][nf], 0, 0, 0);
    }
#pragma unroll
    for (int mf = 0; mf < 2; mf++)
#pragma unroll
      for (int nf = 0; nf < 4; nf++) sc[mf][nf] *= scale;

    // online softmax: row = g*4+r lives in the 16 lanes of group g
#pragma unroll
    for (int mf = 0; mf < 2; mf++)
#pragma unroll
      for (int r = 0; r < 4; r++) {
        float mx = fmaxf(fmaxf(sc[mf][0][r], sc[mf][1][r]), fmaxf(sc[mf][2][r], sc[mf][3][r]));
#pragma unroll
        for (int off = 1; off < 16; off <<= 1) mx = fmaxf(mx, __shfl_xor(mx, off));
        float mo = m_i[mf][r];
        float mn = fmaxf(mo, mx);
        float alpha = __expf(mo - mn);
        float rs = 0.f;
#pragma unroll
        for (int nf = 0; nf < 4; nf++) {
          float p = __expf(sc[mf][nf][r] - mn);
          sc[mf][nf][r] = p;
          rs += p;
        }
#pragma unroll
        for (int off = 1; off < 16; off <<= 1) rs += __shfl_xor(rs, off);
        m_i[mf][r] = mn;
        l_i[mf][r] = l_i[mf][r] * alpha + rs;
#pragma unroll
        for (int ef = 0; ef < 8; ef++) accO[mf][ef][r] *= alpha;
        int prow = wave * 32 + mf * 16 + g * 4 + r;
#pragma unroll
        for (int nf = 0; nf < 4; nf++) ps[prow][nf * 16 + l16] = (__bf16)sc[mf][nf][r];
      }

    __syncthreads();   // order P-writes before punned P-reads

    // PV: wave reads only its own 32 ps rows
#pragma unroll
    for (int kk = 0; kk < 2; kk++) {
      bf16x8 pf[2];
#pragma unroll
      for (int mf = 0; mf < 2; mf++) pf[mf] = ld16v(&ps[wave * 32 + mf * 16 + l16][kk * 32 + g * 8]);
#pragma unroll
      for (int ef = 0; ef < 8; ef++) {
        bf16x8 vf = ld16v(&vs[ef * 16 + l16][kk * 32 + g * 8]);
#pragma unroll
        for (int mf = 0; mf < 2; mf++)
          accO[mf][ef] = __builtin_amdgcn_mfma_f32_16x16x32_bf16(pf[mf], vf, accO[mf][ef], 0, 0, 0);
      }
    }
  }

#pragma unroll
  for (int mf = 0; mf < 2; mf++)
#pragma unroll
    for (int ef = 0; ef < 8; ef++)
#pragma unroll
      for (int r = 0; r < 4; r++) {
        int row = q0 + wave * 32 + mf * 16 + g * 4 + r;
        int col = h * 128 + ef * 16 + l16;
        o[(size_t)row * 1024 + col] = (__bf16)(accO[mf][ef][r] / l_i[mf][r]);
      }
}

extern "C" void kernel_launch(void* const* d_in, const int* in_sizes, int n_in,
                              void* d_out, int out_size, void* d_ws, size_t ws_size,
                              hipStream_t stream) {
  const float* Q   = (const float*)d_in[0];
  const float* Ksr = (const float*)d_in[1];
  const float* Vsr = (const float*)d_in[2];
  const float* Wq  = (const float*)d_in[3];
  const float* bq  = (const float*)d_in[4];
  const float* Wk  = (const float*)d_in[5];
  const float* bk  = (const float*)d_in[6];
  const float* Wv  = (const float*)d_in[7];
  const float* bv  = (const float*)d_in[8];
  const float* Wo  = (const float*)d_in[9];
  const float* bo  = (const float*)d_in[10];
  __bf16* ws = (__bf16*)d_ws;
  const size_t MB = 1024 * 1024;
  __bf16* qb  = ws;             // [8192,1024]
  __bf16* kb  = ws + 8  * MB;   // [2048,1024]
  __bf16* vtb = ws + 10 * MB;   // [1024,2048] = v^T
  __bf16* at  = ws + 12 * MB;   // [8192,1024]
  __bf16* WqT = ws + 20 * MB;   // [1024,1024]
  __bf16* WkT = ws + 21 * MB;   // [1024,4096]
  __bf16* WvT = ws + 25 * MB;   // [1024,4096]
  __bf16* WoT = ws + 29 * MB;   // [4096,1024]

  transpose_k<<<dim3(32, 32),  256, 0, stream>>>(Wq, WqT, 1024, 1024);
  transpose_k<<<dim3(32, 128), 256, 0, stream>>>(Wk, WkT, 4096, 1024);
  transpose_k<<<dim3(32, 128), 256, 0, stream>>>(Wv, WvT, 4096, 1024);
  transpose_k<<<dim3(128, 32), 256, 0, stream>>>(Wo, WoT, 1024, 4096);

  gemm_f_b<<<dim3(64, 8), 256, 0, stream>>>(Q, WqT, bq, qb, 8192, 1024, 1024, 1024, 0);
  gemm_kv<<<dim3(16, 8, 2), 256, 0, stream>>>(Ksr, WkT, bk, kb, Vsr, WvT, bv, vtb);
  attn_k<<<dim3(64, 8), 256, 0, stream>>>(qb, kb, vtb, at);
  gemm_b_f<<<dim3(64, 32), 256, 0, stream>>>(at, WoT, bo, (float*)d_out, 8192, 4096, 1024, 1024, 0);
}

// Round 4
// 721.001 us; speedup vs baseline: 1.0156x; 1.0156x over previous
//
#include <hip/hip_runtime.h>
#include <hip/hip_bf16.h>

// ReprogrammingLayer: q=QWq+bq; k=KsWk+bk; v=VsWv+bv (8 heads, E=128);
// A=softmax(qk^T/sqrt(512)); out=(Av)Wo+bo.
// I/O FP32 (reference dtypes); internal bf16 MFMA + fp32 accum (2% threshold).
//
// ws layout (bf16 elems, peak 33M = 66MB):
//   qb[8M]@0 | kb[2M]@8M | vtb[2M]@10M | at[8M]@12M
//   WqT[1M]@20M | WkT[4M]@21M | WvT[4M]@25M | WoT[4M]@29M

typedef __bf16 bf16x8 __attribute__((ext_vector_type(8)));
typedef float  f32x4  __attribute__((ext_vector_type(4)));

union V16 { uint4 u; bf16x8 v; };
__device__ __forceinline__ bf16x8 ld16v(const void* p) {
  V16 t; t.u = *(const uint4*)p; return t.v;
}
__device__ __forceinline__ uint4 pack8(float4 a, float4 b) {
  V16 t;
  t.v[0] = (__bf16)a.x; t.v[1] = (__bf16)a.y; t.v[2] = (__bf16)a.z; t.v[3] = (__bf16)a.w;
  t.v[4] = (__bf16)b.x; t.v[5] = (__bf16)b.y; t.v[6] = (__bf16)b.z; t.v[7] = (__bf16)b.w;
  return t.u;
}
// async global->LDS DMA, 16B/lane; LDS dest = wave-uniform base + lane*16
__device__ __forceinline__ void dma16(const void* g, void* l) {
  __builtin_amdgcn_global_load_lds(
      (const __attribute__((address_space(1))) unsigned int*)g,
      (__attribute__((address_space(3))) unsigned int*)l, 16, 0, 0);
}
// XOR-swizzled 16B-chunk index for a 128x32 bf16 tile (4 chunks/row).
// 8 distinct bank-groups over any 16 consecutive rows -> 2-way (free).
__device__ __forceinline__ int chunk_of(int row, int gc) {
  return row * 4 + (gc ^ ((row >> 1) & 3));
}

// -------- weight transpose+convert: W[K][N] fp32 -> Wt[N][K] bf16 --------
__global__ __launch_bounds__(256) void transpose_k(const float* __restrict__ W,
                                                   __bf16* __restrict__ Wt, int K, int N) {
  __shared__ __bf16 t[32][33];
  int tx = threadIdx.x & 31, ty = threadIdx.x >> 5;
  int n0 = blockIdx.x * 32, k0 = blockIdx.y * 32;
#pragma unroll
  for (int r = 0; r < 32; r += 8) t[ty + r][tx] = (__bf16)W[(size_t)(k0 + ty + r) * N + n0 + tx];
  __syncthreads();
#pragma unroll
  for (int r = 0; r < 32; r += 8) Wt[(size_t)(n0 + ty + r) * K + k0 + tx] = t[tx][ty + r];
}

// -------- GEMM core: C = A[M,K] @ Bt[N,K]^T + bias --------
// 128x128 tile, BK=32, 4 waves 2x2, 4x4 16x16x32 bf16 mfma frags.
// LDS: unpadded XOR-swizzled 128x32 tiles (8KB each).
// B staged via global_load_lds (m97 pattern). A: DMA when bf16, manual
// fp32->bf16 convert into the same swizzled layout when fp32.
template <typename AT, typename CT>
__device__ __forceinline__ void gemm_core(__bf16* As, __bf16* Bs,
                                          const AT* __restrict__ A,
                                          const __bf16* __restrict__ Bt,
                                          const float* __restrict__ bias,
                                          CT* __restrict__ C,
                                          int M, int N, int K, int lda, int trans,
                                          int m0, int n0) {
  const int tid = threadIdx.x;
  const int lane = tid & 63, wave = tid >> 6;
  const int g = lane >> 4, l16 = lane & 15;
  const int wr = wave >> 1, wc = wave & 1;
  // k-invariant swizzled fragment offsets (bf16 elems)
  int aoff[4], boff[4];
#pragma unroll
  for (int mf = 0; mf < 4; mf++) aoff[mf] = chunk_of(wr * 64 + mf * 16 + l16, g) * 8;
#pragma unroll
  for (int nf = 0; nf < 4; nf++) boff[nf] = chunk_of(wc * 64 + nf * 16 + l16, g) * 8;

  f32x4 acc[4][4] = {};
  for (int k0 = 0; k0 < K; k0 += 32) {
    __syncthreads();
    if constexpr (sizeof(AT) == 2) {       // bf16 A: DMA, 2 issues/wave
#pragma unroll
      for (int rnd = 0; rnd < 2; rnd++) {
        int cstart = wave * 128 + rnd * 64;
        int p = cstart + lane;
        int row = p >> 2, gc = (p & 3) ^ ((row >> 1) & 3);
        dma16((const __bf16*)A + (size_t)(m0 + row) * lda + k0 + gc * 8,
              As + (size_t)cstart * 8);
      }
    } else {                               // fp32 A: load+convert, 2 chunks/thread
#pragma unroll
      for (int i = 0; i < 2; i++) {
        int p = tid + i * 256;
        int row = p >> 2, gc = (p & 3) ^ ((row >> 1) & 3);
        const float* ap = (const float*)A + (size_t)(m0 + row) * lda + k0 + gc * 8;
        float4 f0 = *(const float4*)ap;
        float4 f1 = *(const float4*)(ap + 4);
        *(uint4*)(As + p * 8) = pack8(f0, f1);
      }
    }
#pragma unroll
    for (int rnd = 0; rnd < 2; rnd++) {    // B: always bf16 DMA
      int cstart = wave * 128 + rnd * 64;
      int p = cstart + lane;
      int row = p >> 2, gc = (p & 3) ^ ((row >> 1) & 3);
      dma16(Bt + (size_t)(n0 + row) * (size_t)K + k0 + gc * 8,
            Bs + (size_t)cstart * 8);
    }
    __syncthreads();
    bf16x8 af[4], bff[4];
#pragma unroll
    for (int mf = 0; mf < 4; mf++) af[mf]  = ld16v(As + aoff[mf]);
#pragma unroll
    for (int nf = 0; nf < 4; nf++) bff[nf] = ld16v(Bs + boff[nf]);
#pragma unroll
    for (int mf = 0; mf < 4; mf++)
#pragma unroll
      for (int nf = 0; nf < 4; nf++)
        acc[mf][nf] = __builtin_amdgcn_mfma_f32_16x16x32_bf16(af[mf], bff[nf], acc[mf][nf], 0, 0, 0);
  }
#pragma unroll
  for (int nf = 0; nf < 4; nf++) {
    int col = n0 + wc * 64 + nf * 16 + l16;
    float bv = bias[col];
#pragma unroll
    for (int mf = 0; mf < 4; mf++) {
      int rowb = m0 + wr * 64 + mf * 16 + g * 4;
      if constexpr (sizeof(CT) == 2) {
        if (trans) {
          union { __bf16 h[4]; uint2 u; } pk;
#pragma unroll
          for (int r = 0; r < 4; r++) pk.h[r] = (__bf16)(acc[mf][nf][r] + bv);
          *(uint2*)&((__bf16*)C)[(size_t)col * M + rowb] = pk.u;   // C^T[n][m]
        } else {
#pragma unroll
          for (int r = 0; r < 4; r++)
            ((__bf16*)C)[(size_t)(rowb + r) * N + col] = (__bf16)(acc[mf][nf][r] + bv);
        }
      } else {
#pragma unroll
        for (int r = 0; r < 4; r++)
          ((float*)C)[(size_t)(rowb + r) * N + col] = acc[mf][nf][r] + bv;
      }
    }
  }
}

__global__ __launch_bounds__(256) void gemm_f_b(const float* __restrict__ A,
                                                const __bf16* __restrict__ Bt,
                                                const float* __restrict__ bias,
                                                __bf16* __restrict__ C,
                                                int M, int N, int K, int lda, int trans) {
  __shared__ __align__(16) __bf16 As[128 * 32];
  __shared__ __align__(16) __bf16 Bs[128 * 32];
  gemm_core<float, __bf16>(As, Bs, A, Bt, bias, C, M, N, K, lda, trans,
                           blockIdx.x * 128, blockIdx.y * 128);
}

__global__ __launch_bounds__(256) void gemm_b_f(const __bf16* __restrict__ A,
                                                const __bf16* __restrict__ Bt,
                                                const float* __restrict__ bias,
                                                float* __restrict__ C,
                                                int M, int N, int K, int lda, int trans) {
  __shared__ __align__(16) __bf16 As[128 * 32];
  __shared__ __align__(16) __bf16 Bs[128 * 32];
  gemm_core<__bf16, float>(As, Bs, A, Bt, bias, C, M, N, K, lda, trans,
                           blockIdx.x * 128, blockIdx.y * 128);
}

__global__ __launch_bounds__(256) void gemm_kv(const float* __restrict__ A0, const __bf16* __restrict__ B0t,
                                               const float* __restrict__ b0, __bf16* __restrict__ C0,
                                               const float* __restrict__ A1, const __bf16* __restrict__ B1t,
                                               const float* __restrict__ b1, __bf16* __restrict__ C1) {
  __shared__ __align__(16) __bf16 As[128 * 32];
  __shared__ __align__(16) __bf16 Bs[128 * 32];
  if (blockIdx.z == 0)
    gemm_core<float, __bf16>(As, Bs, A0, B0t, b0, C0, 2048, 1024, 4096, 4096, 0,
                             blockIdx.x * 128, blockIdx.y * 128);
  else
    gemm_core<float, __bf16>(As, Bs, A1, B1t, b1, C1, 2048, 1024, 4096, 4096, 1,
                             blockIdx.x * 128, blockIdx.y * 128);
}

// -------- flash attention --------
// grid (64 q-blocks, 8 heads), 256 thr; 128 q-rows/block, S-tile 64.
// LDS cut 54->37 KB by aliasing ps (P matrix) onto ks (K tile): ps is only
// written AFTER the last ks read of the iteration (barrier enforces).
// 160/37 -> 4 blocks/CU, occupancy 22% -> ~44% (round-3 bottleneck).
__global__ __launch_bounds__(256) void attn_k(const __bf16* __restrict__ q,
                                              const __bf16* __restrict__ k,
                                              const __bf16* __restrict__ vt,
                                              __bf16* __restrict__ o) {
  __shared__ union {
    __bf16 ks[64][136];   // K tile [s][e], +8 pad (272B rows: 2-way free)
    __bf16 ps[128][72];   // P tile [q][s], written after ks is dead
  } u;
  __shared__ __bf16 vs[128][72];   // V^T tile [e][s]
  const int tid = threadIdx.x, lane = tid & 63, wave = tid >> 6;
  const int g = lane >> 4, l16 = lane & 15;
  const int h = blockIdx.y, q0 = blockIdx.x * 128;
  const float scale = 0.044194173824159216f;  // 1/sqrt(512): d_llm//H per reference

  bf16x8 qf[2][4];
#pragma unroll
  for (int mf = 0; mf < 2; mf++)
#pragma unroll
    for (int kk = 0; kk < 4; kk++) {
      int row = q0 + wave * 32 + mf * 16 + l16;
      qf[mf][kk] = ld16v(q + (size_t)row * 1024 + h * 128 + kk * 32 + g * 8);
    }

  f32x4 accO[2][8] = {};
  float m_i[2][4], l_i[2][4];
#pragma unroll
  for (int a = 0; a < 2; a++)
#pragma unroll
    for (int b = 0; b < 4; b++) { m_i[a][b] = -1e30f; l_i[a][b] = 0.f; }

  for (int s0 = 0; s0 < 2048; s0 += 64) {
    __syncthreads();                        // (1) prior PV reads of u.ps/vs done
#pragma unroll
    for (int i = 0; i < 4; i++) {           // stage K [64s][128e], V^T [128e][64s]
      int c = tid + i * 256;
      { int row = c >> 4, col = (c & 15) * 8;
        *(uint4*)&u.ks[row][col] = *(const uint4*)(k + (size_t)(s0 + row) * 1024 + h * 128 + col); }
      { int row = c >> 3, col = (c & 7) * 8;
        *(uint4*)&vs[row][col] = *(const uint4*)(vt + (size_t)(h * 128 + row) * 2048 + s0 + col); }
    }
    __syncthreads();                        // (2) staging visible

    f32x4 sc[2][4] = {};
#pragma unroll
    for (int kk = 0; kk < 4; kk++) {        // QK^T, contract over e=128
      bf16x8 kf[4];
#pragma unroll
      for (int nf = 0; nf < 4; nf++) kf[nf] = ld16v(&u.ks[nf * 16 + l16][kk * 32 + g * 8]);
#pragma unroll
      for (int mf = 0; mf < 2; mf++)
#pragma unroll
        for (int nf = 0; nf < 4; nf++)
          sc[mf][nf] = __builtin_amdgcn_mfma_f32_16x16x32_bf16(qf[mf][kk], kf[nf], sc[mf][nf], 0, 0, 0);
    }
#pragma unroll
    for (int mf = 0; mf < 2; mf++)
#pragma unroll
      for (int nf = 0; nf < 4; nf++) sc[mf][nf] *= scale;

    // online softmax in regs (no LDS): row g*4+r lives in 16 lanes of group g
#pragma unroll
    for (int mf = 0; mf < 2; mf++)
#pragma unroll
      for (int r = 0; r < 4; r++) {
        float mx = fmaxf(fmaxf(sc[mf][0][r], sc[mf][1][r]), fmaxf(sc[mf][2][r], sc[mf][3][r]));
#pragma unroll
        for (int off = 1; off < 16; off <<= 1) mx = fmaxf(mx, __shfl_xor(mx, off));
        float mo = m_i[mf][r];
        float mn = fmaxf(mo, mx);
        float alpha = __expf(mo - mn);
        float rs = 0.f;
#pragma unroll
        for (int nf = 0; nf < 4; nf++) {
          float p = __expf(sc[mf][nf][r] - mn);
          sc[mf][nf][r] = p;
          rs += p;
        }
#pragma unroll
        for (int off = 1; off < 16; off <<= 1) rs += __shfl_xor(rs, off);
        m_i[mf][r] = mn;
        l_i[mf][r] = l_i[mf][r] * alpha + rs;
#pragma unroll
        for (int ef = 0; ef < 8; ef++) accO[mf][ef][r] *= alpha;
      }

    __syncthreads();                        // (3) all ks reads done; u.ps safe

#pragma unroll
    for (int mf = 0; mf < 2; mf++)
#pragma unroll
      for (int r = 0; r < 4; r++) {
        int prow = wave * 32 + mf * 16 + g * 4 + r;
#pragma unroll
        for (int nf = 0; nf < 4; nf++) u.ps[prow][nf * 16 + l16] = (__bf16)sc[mf][nf][r];
      }

    // PV: wave reads only its own 32 ps rows (same-wave LDS order suffices)
#pragma unroll
    for (int kk = 0; kk < 2; kk++) {
      bf16x8 pf[2];
#pragma unroll
      for (int mf = 0; mf < 2; mf++) pf[mf] = ld16v(&u.ps[wave * 32 + mf * 16 + l16][kk * 32 + g * 8]);
#pragma unroll
      for (int ef = 0; ef < 8; ef++) {
        bf16x8 vf = ld16v(&vs[ef * 16 + l16][kk * 32 + g * 8]);
#pragma unroll
        for (int mf = 0; mf < 2; mf++)
          accO[mf][ef] = __builtin_amdgcn_mfma_f32_16x16x32_bf16(pf[mf], vf, accO[mf][ef], 0, 0, 0);
      }
    }
  }

#pragma unroll
  for (int mf = 0; mf < 2; mf++)
#pragma unroll
    for (int ef = 0; ef < 8; ef++)
#pragma unroll
      for (int r = 0; r < 4; r++) {
        int row = q0 + wave * 32 + mf * 16 + g * 4 + r;
        int col = h * 128 + ef * 16 + l16;
        o[(size_t)row * 1024 + col] = (__bf16)(accO[mf][ef][r] / l_i[mf][r]);
      }
}

extern "C" void kernel_launch(void* const* d_in, const int* in_sizes, int n_in,
                              void* d_out, int out_size, void* d_ws, size_t ws_size,
                              hipStream_t stream) {
  const float* Q   = (const float*)d_in[0];
  const float* Ksr = (const float*)d_in[1];
  const float* Vsr = (const float*)d_in[2];
  const float* Wq  = (const float*)d_in[3];
  const float* bq  = (const float*)d_in[4];
  const float* Wk  = (const float*)d_in[5];
  const float* bk  = (const float*)d_in[6];
  const float* Wv  = (const float*)d_in[7];
  const float* bv  = (const float*)d_in[8];
  const float* Wo  = (const float*)d_in[9];
  const float* bo  = (const float*)d_in[10];
  __bf16* ws = (__bf16*)d_ws;
  const size_t MB = 1024 * 1024;
  __bf16* qb  = ws;             // [8192,1024]
  __bf16* kb  = ws + 8  * MB;   // [2048,1024]
  __bf16* vtb = ws + 10 * MB;   // [1024,2048] = v^T
  __bf16* at  = ws + 12 * MB;   // [8192,1024]
  __bf16* WqT = ws + 20 * MB;   // [1024,1024]
  __bf16* WkT = ws + 21 * MB;   // [1024,4096]
  __bf16* WvT = ws + 25 * MB;   // [1024,4096]
  __bf16* WoT = ws + 29 * MB;   // [4096,1024]

  transpose_k<<<dim3(32, 32),  256, 0, stream>>>(Wq, WqT, 1024, 1024);
  transpose_k<<<dim3(32, 128), 256, 0, stream>>>(Wk, WkT, 4096, 1024);
  transpose_k<<<dim3(32, 128), 256, 0, stream>>>(Wv, WvT, 4096, 1024);
  transpose_k<<<dim3(128, 32), 256, 0, stream>>>(Wo, WoT, 1024, 4096);

  gemm_f_b<<<dim3(64, 8), 256, 0, stream>>>(Q, WqT, bq, qb, 8192, 1024, 1024, 1024, 0);
  gemm_kv<<<dim3(16, 8, 2), 256, 0, stream>>>(Ksr, WkT, bk, kb, Vsr, WvT, bv, vtb);
  attn_k<<<dim3(64, 8), 256, 0, stream>>>(qb, kb, vtb, at);
  gemm_b_f<<<dim3(64, 32), 256, 0, stream>>>(at, WoT, bo, (float*)d_out, 8192, 4096, 1024, 1024, 0);
}